// Round 16
// baseline (573.860 us; speedup 1.0000x reference)
//
#include <hip/hip_runtime.h>
#include <cstdint>

#define Tt 1024
#define Hh 15
#define Ii 10
#define Oo 128
#define Bb 512

typedef float v4f __attribute__((ext_vector_type(4)));
typedef float v2f __attribute__((ext_vector_type(2)));

__device__ __forceinline__ float sigmoidf_(float x) {
    return 1.0f / (1.0f + __expf(-x));
}
__device__ __forceinline__ float tanhf_(float x) {
    return 1.0f - 2.0f / (__expf(2.0f * x) + 1.0f);
}

// DPP row-rotate of a float within each 16-lane row. j must be a literal.
#define ROT(x, j) __int_as_float(__builtin_amdgcn_update_dpp( \
    0, __float_as_int(x), 0x120 + (j), 0xF, 0xF, true))

// Kernel A: sequential recurrence, GATE-SPLIT.
//
// R13 falsified the weight-reload theory (LDS tables: VGPR 56->40 but
// 516->579 cyc/step). Counters say the wave is ISSUE-bound: ~75% of the
// occupied SIMD's cycles are VALU issue (~200 inst/step, dominated by the
// 48 per-lane gate FMAs). Fix = fewer instructions per lane per step:
//
//   1 batch per wave; row 0/1/2 of the wave = gate r/z/n (row 3 = dup r).
//   Every row holds a full copy of h -> DPP rotations unchanged.
//   Each lane computes ONLY its gate's 16-tap dot: 8 v_pk_fma_f32.
//   3 parallel __shfl (ds_bpermute) share the gate sums to all lanes;
//   the scalar tail (2 sigmoids + tanh + blend) is computed redundantly
//   in every lane -> hnew lands in every row's registers for step t+1.
//   Per-step: ~16 DPP + 8 pk_fma + 3 adds + 3 shfl + ~18 tail + store
//   ~= 60-70 inst vs ~200 before.
//
// Weights: 16 rotated taps/lane (8 v2f regs), register-resident. No LDS.
__global__ __launch_bounds__(64, 1) void gru_recur(
    const float* __restrict__ feed, const float* __restrict__ h0,
    const float* __restrict__ W_ih, const float* __restrict__ W_hh,
    const float* __restrict__ b_ih, const float* __restrict__ b_hh,
    float* __restrict__ hs)
{
    const int lane = threadIdx.x;      // 0..63
    const int row  = lane >> 4;        // 0..3 -> gate r,z,n,(dup r)
    const int u    = lane & 15;        // hidden unit (u==15 inert)
    const int uu   = (u < Hh) ? u : 0;
    const int gate = (row < 3) ? row : 0;
    const int b    = blockIdx.x;       // one batch per wave

    // Probe DPP row_ror source direction once.
    int pr = __builtin_amdgcn_update_dpp(0, lane & 15, 0x121, 0xF, 0xF, true);
    int p0 = __builtin_amdgcn_readfirstlane(pr);
    const int dir = (p0 == 1) ? 1 : 15;   // 15*j == -j (mod 16)

    // Per-lane rotated taps for (gate, u), v2f-packed. Invalid taps zeroed.
    v2f Wp[8];
    #pragma unroll
    for (int jp = 0; jp < 8; ++jp) {
        float w0 = 0.0f, w1 = 0.0f;
        {
            int k = (uu + dir * (2 * jp)) & 15;
            if (u < Hh && k < Hh) w0 = W_hh[(uu + gate * Hh) * Hh + k];
        }
        {
            int k = (uu + dir * (2 * jp + 1)) & 15;
            if (u < Hh && k < Hh) w1 = W_hh[(uu + gate * Hh) * Hh + k];
        }
        Wp[jp] = (v2f){w0, w1};
    }

    // Gate seeds (same math as baseline): r,z fold b_ih+b_hh+x@W_ih;
    // n accumulator seeds with b_hh n-part; i_n (cn) is applied in the tail.
    float cr = b_ih[uu]          + b_hh[uu];
    float cz = b_ih[uu + Hh]     + b_hh[uu + Hh];
    float cn = b_ih[uu + 2 * Hh];
    float bn = b_hh[uu + 2 * Hh];
    #pragma unroll
    for (int i = 0; i < Ii; ++i) {
        float x = feed[b * Ii + i];
        cr += x * W_ih[(uu         ) * Ii + i];
        cz += x * W_ih[(uu +     Hh) * Ii + i];
        cn += x * W_ih[(uu + 2 * Hh) * Ii + i];
    }
    const float seed = (gate == 0) ? cr : (gate == 1) ? cz : bn;

    float hcur = (u < Hh) ? h0[b * Hh + uu] : 0.0f;
    size_t off = (size_t)b * 16 + u;

    for (int t = 0; t < Tt; ++t) {
        // Rotate h within each row, packed in v2f pairs for pk-FMA.
        v2f h2[8];
        h2[0].x = hcur;          h2[0].y = ROT(hcur, 1);
        h2[1].x = ROT(hcur, 2);  h2[1].y = ROT(hcur, 3);
        h2[2].x = ROT(hcur, 4);  h2[2].y = ROT(hcur, 5);
        h2[3].x = ROT(hcur, 6);  h2[3].y = ROT(hcur, 7);
        h2[4].x = ROT(hcur, 8);  h2[4].y = ROT(hcur, 9);
        h2[5].x = ROT(hcur, 10); h2[5].y = ROT(hcur, 11);
        h2[6].x = ROT(hcur, 12); h2[6].y = ROT(hcur, 13);
        h2[7].x = ROT(hcur, 14); h2[7].y = ROT(hcur, 15);

        // This lane's gate dot: 8 packed FMAs, 2-way split accumulators.
        v2f a0 = (v2f){seed, 0.0f};
        v2f a1 = (v2f){0.0f, 0.0f};
        a0 += Wp[0] * h2[0];  a1 += Wp[1] * h2[1];
        a0 += Wp[2] * h2[2];  a1 += Wp[3] * h2[3];
        a0 += Wp[4] * h2[4];  a1 += Wp[5] * h2[5];
        a0 += Wp[6] * h2[6];  a1 += Wp[7] * h2[7];
        v2f s2 = a0 + a1;
        float a = s2.x + s2.y;

        // Share the three gate sums to every lane (3 parallel bpermutes).
        float ga_r = __shfl(a, u);
        float ga_z = __shfl(a, u + 16);
        float ga_n = __shfl(a, u + 32);

        // Redundant scalar tail in all lanes (keeps h in-register everywhere).
        float r = sigmoidf_(ga_r);
        float z = sigmoidf_(ga_z);
        float n = tanhf_(cn + r * ga_n);
        float hnew = n + z * (hcur - n);

        if (lane < 16) hs[off] = hnew;   // row 0 stores (u==15 pad junk, finite)
        off += (size_t)Bb * 16;
        hcur = hnew;
    }
}

__device__ __forceinline__ v4f ntload4(const float* p) {
    return __builtin_nontemporal_load((const v4f*)p);
}

// Kernel B: out[p,o] = sigmoid(hs[p,:] . W_out[o,:] + b_out[o]).
// 2-deep software pipeline; nontemporal streaming loads/stores.
// (Verbatim from the 527us baseline — measured ~88us, ~3.4 TB/s.)
__global__ __launch_bounds__(256) void gru_proj(
    const float* __restrict__ hs, const float* __restrict__ W_out,
    const float* __restrict__ b_out, float* __restrict__ out)
{
    const int q  = threadIdx.x & 31;   // o-quad
    const int gg = threadIdx.x >> 5;   // p-slot within block (0..7)
    const int o0 = q * 4;

    float w[4][Hh];
    float bo[4];
    #pragma unroll
    for (int j = 0; j < 4; ++j) {
        bo[j] = b_out[o0 + j];
        #pragma unroll
        for (int k = 0; k < Hh; ++k) w[j][k] = W_out[(o0 + j) * Hh + k];
    }

    const int P = Tt * Bb;
    const int stride = gridDim.x * 8;
    int p = blockIdx.x * 8 + gg;
    if (p >= P) return;

    const float* hp = hs + (size_t)p * 16;
    v4f A = ntload4(hp), B_ = ntload4(hp + 4), C = ntload4(hp + 8), D = ntload4(hp + 12);

    while (true) {
        int pn = p + stride;
        bool more = pn < P;
        const float* hpn = hs + (size_t)(more ? pn : p) * 16;
        v4f A2 = ntload4(hpn), B2 = ntload4(hpn + 4),
            C2 = ntload4(hpn + 8), D2 = ntload4(hpn + 12);

        float h[Hh] = {A.x, A.y, A.z, A.w, B_.x, B_.y, B_.z, B_.w,
                       C.x, C.y, C.z, C.w, D.x, D.y, D.z};
        float acc[4];
        #pragma unroll
        for (int j = 0; j < 4; ++j) {
            float s0 = bo[j], s1 = 0.f;
            #pragma unroll
            for (int k = 0; k < Hh; k += 2) s0 += h[k] * w[j][k];
            #pragma unroll
            for (int k = 1; k < Hh; k += 2) s1 += h[k] * w[j][k];
            acc[j] = sigmoidf_(s0 + s1);
        }
        v4f res = {acc[0], acc[1], acc[2], acc[3]};
        __builtin_nontemporal_store(res, (v4f*)(out + (size_t)p * (size_t)Oo + o0));

        if (!more) break;
        p = pn; A = A2; B_ = B2; C = C2; D = D2;
    }
}

extern "C" void kernel_launch(void* const* d_in, const int* in_sizes, int n_in,
                              void* d_out, int out_size, void* d_ws, size_t ws_size,
                              hipStream_t stream) {
    const float* feed  = (const float*)d_in[0];
    const float* h0    = (const float*)d_in[1];
    const float* W_ih  = (const float*)d_in[2];
    const float* W_hh  = (const float*)d_in[3];
    const float* b_ih  = (const float*)d_in[4];
    const float* b_hh  = (const float*)d_in[5];
    const float* W_out = (const float*)d_in[6];
    const float* b_out = (const float*)d_in[7];
    float* out = (float*)d_out;
    float* hs  = (float*)d_ws;   // [T][B][16] floats = 33.5 MB

    gru_recur<<<Bb, 64, 0, stream>>>(feed, h0, W_ih, W_hh, b_ih, b_hh, hs);
    gru_proj<<<2048, 256, 0, stream>>>(hs, W_out, b_out, out);
}